// Round 5
// baseline (908.631 us; speedup 1.0000x reference)
//
#include <hip/hip_runtime.h>
#include <math.h>

// RecursiveAttentiveEncoder — MoE-sorted MFMA, ws_size-adaptive chunking.
// R4 post-mortem: absmax 6.5e+35 (finite-huge) proved the float inputs are
// FLOAT32, not bf16 — reading f32 as bf16 pairs injects mantissa-bits-as-bf16
// garbage with random exponents (up to e38). R5: float inputs read as float*,
// converted once to bf16 (weights transposed, ent_emb copied) for the MFMA
// path; biases added in fp32 epilogue from the raw float arrays; attention is
// pure fp32 on raw float weights; output written as float32.
//
// Pipeline: counting-sort rows by expert id (wave-ballot-aggregated atomics),
// then per-bin fused relu(x@W1+b1)@W2+b2 via mfma_f32_16x16x32_bf16 with
// h^T = W1t*x^T (weights as A-operand; activations as K-contiguous B-operand).
// Tree levels processed in chunks of CB trees to bound workspace use.

typedef unsigned short u16;
typedef unsigned int   u32;
typedef unsigned long long u64;
typedef __attribute__((ext_vector_type(8))) short v8s;   // 8 bf16 (4 VGPRs)
typedef __attribute__((ext_vector_type(4))) float f32x4; // MFMA acc

__device__ __forceinline__ float b2f(u16 u) { return __uint_as_float(((u32)u) << 16); }
__device__ __forceinline__ u16 f2b(float f) {
  f = (f == f) ? f : 0.f;                    // NaN squash (hygiene)
  u32 x = __float_as_uint(f);
  u32 r = x + 0x7fffu + ((x >> 16) & 1u);
  return (u16)(r >> 16);
}

#define NTREE 34816   // B*T_TREES = 1024*34
#define RLEAF 9216    // B*(GT_MAX+1)

// ==================== per-chunk expert sort (node levels) ====================
// gid in [0,15*CB): [0,8CB)=lvl0, [8CB,12CB)=lvl1, [12CB,14CB)=lvl2,
// [14CB,15CB)=lvl3. CB multiple of 32 -> every boundary 64-aligned -> each
// wave is level-uniform (tail lanes get id=-1 and never write).
__global__ __launch_bounds__(256) void perm_chunk_k(
    const int* __restrict__ nf, int* __restrict__ cnt, int* __restrict__ perm,
    const int CB, const int bt0)
{
  const int gid = blockIdx.x * 256 + threadIdx.x;
  int id = -1, lr = 0, rows = CB, cofs = 12, pofs = 56 * CB, ioff = 14, shift = 0;
  if (gid < 8 * CB)       { lr = gid;          rows = 8*CB; cofs = 0;  pofs = 0;      ioff = 0;  shift = 3; }
  else if (gid < 12 * CB) { lr = gid - 8*CB;   rows = 4*CB; cofs = 4;  pofs = 32*CB;  ioff = 8;  shift = 2; }
  else if (gid < 14 * CB) { lr = gid - 12*CB;  rows = 2*CB; cofs = 8;  pofs = 48*CB;  ioff = 12; shift = 1; }
  else if (gid < 15 * CB) { lr = gid - 14*CB;  /* lvl3 defaults above */              }
  if (gid < 15 * CB) {
    int bt = bt0 + (lr >> shift);
    int n  = lr & ((1 << shift) - 1);
    id = nf[bt * 15 + ioff + n];
  }
  const int lane = threadIdx.x & 63;
  for (int e = 0; e < 4; ++e) {
    u64 m = __ballot(id == e);
    if (!m) continue;
    int leader = __builtin_ctzll(m);
    int bp = 0;
    if (lane == leader) bp = atomicAdd(&cnt[cofs + e], (int)__popcll(m));
    bp = __shfl(bp, leader);
    if (id == e)
      perm[pofs + e * rows + bp + (int)__popcll(m & ((1ull << lane) - 1ull))] = lr;
  }
}

// ==================== leaf-stage expert sort ====================
__global__ __launch_bounds__(256) void leaf_perm_k(
    const int* __restrict__ lf, int* __restrict__ cnt, int* __restrict__ perm)
{
  const int gid = blockIdx.x * 256 + threadIdx.x;   // 36*256 = 9216 exact
  const int id = lf[gid];
  const int lane = threadIdx.x & 63;
  for (int e = 0; e < 3; ++e) {
    u64 m = __ballot(id == e);
    if (!m) continue;
    int leader = __builtin_ctzll(m);
    int bp = 0;
    if (lane == leader) bp = atomicAdd(&cnt[e], (int)__popcll(m));
    bp = __shfl(bp, leader);
    if (id == e)
      perm[e * RLEAF + bp + (int)__popcll(m & ((1ull << lane) - 1ull))] = gid;
  }
}

// ==================== weight convert+transpose (f32 -> bf16) ====================
__global__ __launch_bounds__(256) void transpose_k(
    const float* __restrict__ s0, const float* __restrict__ s1,
    const float* __restrict__ s2, const float* __restrict__ s3,
    const float* __restrict__ s4,
    u16* __restrict__ d0, u16* __restrict__ d1, u16* __restrict__ d2,
    u16* __restrict__ d3, u16* __restrict__ d4)
{
  int idx = blockIdx.x * 256 + threadIdx.x;
  if (idx < 262144) {                       // nf_W1 [4][256][256] -> [e][o][i]
    int e = idx >> 16, r = idx & 65535, o = r >> 8, i = r & 255;
    d0[idx] = f2b(s0[(e << 16) + (i << 8) + o]);
  } else if (idx < 393216) {                // nf_W2 [4][256][128] -> [4][128][256]
    int t = idx - 262144;
    int e = t >> 15, r = t & 32767, o = r >> 8, i = r & 255;
    d1[t] = f2b(s1[(e << 15) + (i << 7) + o]);
  } else if (idx < 786432) {                // lf_W1 [3][256][512] -> [3][512][256]
    int t = idx - 393216;
    int e = t >> 17, r = t & 131071, o = r >> 8, i = r & 255;
    d2[t] = f2b(s2[(e << 17) + (i << 9) + o]);
  } else if (idx < 983040) {                // lf_W2 [3][512][128] -> [3][128][512]
    int t = idx - 786432;
    int e = t >> 16, r = t & 65535, o = r >> 9, i = r & 511;
    d3[t] = f2b(s3[(e << 16) + (i << 7) + o]);
  } else if (idx < 1239040) {               // ent_emb [2000][128] f32 -> bf16
    int t = idx - 983040;
    d4[t] = f2b(s4[t]);
  }
}

// ==================== fused expert MLP ====================
// out[r] = relu(x[r] @ W1[bin] + b1[bin]) @ W2[bin] + b2[bin]
// h^T = W1t(A)*x^T(B); y^T = W2t(A)*h^T(B).   rc is a CHUNK-LOCAL row id.
// MODE 0: x = concat(embB[leaf_idx[bt*16+2n]], [..+2n+1]), bt = bt0+(rc>>3)
// MODE 1: x = src + rc*256 (pair of prev-level rows in the chunk buffer)
// MODE 2: x = roots rows (b*34+16+2g), b = rc/9, g = rc%9 (full roots buffer)
template<int HID, int NEXP, int MODE, int MR>
__global__ __launch_bounds__(256, 2) void mlp_k(
    const u16* __restrict__ src, const int* __restrict__ lidx,
    const u16* __restrict__ emb,
    const int* __restrict__ perm, const int* __restrict__ cnt,
    const int rows, const int bt0,
    const u16* __restrict__ W1t, const float* __restrict__ b1,
    const u16* __restrict__ W2t, const float* __restrict__ b2,
    u16* __restrict__ dst)
{
  constexpr int HSTR = HID + 8;       // +8 bf16 pad: 16B-aligned rows, 2-way banks
  constexpr int NT = MR / 16;         // row tiles (B-operand)
  constexpr int MT1 = HID / 64;       // phase-1 m-tiles per wave
  __shared__ __align__(16) u16 hs[MR * HSTR];

  int bin = -1, tile = 0, cb = 0;
  {
    int rem = blockIdx.x;
    #pragma unroll
    for (int e = 0; e < NEXP; ++e) {
      int ce = cnt[e];
      int tt = (ce + MR - 1) / MR;
      if (bin < 0) {
        if (rem < tt) { bin = e; tile = rem; cb = ce; }
        else rem -= tt;
      }
    }
  }
  if (bin < 0) return;
  const int rbase = tile * MR;
  const int tid = threadIdx.x;
  const int w  = tid >> 6;
  const int lane = tid & 63;
  const int lm = lane & 15;
  const int lq = lane >> 4;

  const u16* rpa[NT]; const u16* rpb[NT]; int rowid[NT];
  #pragma unroll
  for (int n = 0; n < NT; ++n) {
    int rl = rbase + n * 16 + lm;
    int rlc = rl < cb ? rl : (cb - 1);
    int rc = perm[(size_t)bin * rows + rlc];
    rc = rc < 0 ? 0 : (rc >= rows ? rows - 1 : rc);   // defensive
    rowid[n] = (rl < cb) ? rc : -1;
    if (MODE == 0) {
      int bt = bt0 + (rc >> 3), node = rc & 7;
      int ia = lidx[bt * 16 + node * 2];
      int ib = lidx[bt * 16 + node * 2 + 1];
      ia = ia < 0 ? 0 : (ia > 1999 ? 1999 : ia);      // V_ENT=2000, defensive
      ib = ib < 0 ? 0 : (ib > 1999 ? 1999 : ib);
      rpa[n] = emb + (size_t)ia * 128;
      rpb[n] = emb + (size_t)ib * 128;
    } else if (MODE == 1) {
      rpa[n] = src + (size_t)rc * 256;
      rpb[n] = rpa[n] + 128;
    } else {
      int bq = rc / 9, g = rc - bq * 9;
      rpa[n] = src + ((size_t)bq * 34 + 16 + 2 * g) * 128;
      rpb[n] = rpa[n] + 128;
    }
  }

  // ---- phase 1: h^T = W1t * x^T, +b1, relu -> LDS ----
  const u16* __restrict__ Wb = W1t + (size_t)bin * HID * 256;
  f32x4 acc[MT1][NT];
  #pragma unroll
  for (int m = 0; m < MT1; ++m)
    #pragma unroll
    for (int n = 0; n < NT; ++n)
      acc[m][n] = f32x4{0.f, 0.f, 0.f, 0.f};

  #pragma unroll
  for (int k = 0; k < 8; ++k) {             // K=256
    const int ko = k * 32 + lq * 8;
    v8s bfr[NT];
    #pragma unroll
    for (int n = 0; n < NT; ++n) {
      const u16* p = (ko < 128) ? (rpa[n] + ko) : (rpb[n] + (ko - 128));
      bfr[n] = *(const v8s*)p;
    }
    #pragma unroll
    for (int m = 0; m < MT1; ++m) {
      const v8s af = *(const v8s*)(Wb + (size_t)((w * MT1 + m) * 16 + lm) * 256 + ko);
      #pragma unroll
      for (int n = 0; n < NT; ++n)
        acc[m][n] = __builtin_amdgcn_mfma_f32_16x16x32_bf16(af, bfr[n], acc[m][n], 0, 0, 0);
    }
  }
  const float* b1b = b1 + bin * HID;
  #pragma unroll
  for (int m = 0; m < MT1; ++m) {
    const int f = (w * MT1 + m) * 16 + lq * 4;
    float bb0 = b1b[f], bb1 = b1b[f + 1], bb2 = b1b[f + 2], bb3 = b1b[f + 3];
    #pragma unroll
    for (int n = 0; n < NT; ++n) {
      union { u16 h[4]; uint2 v; } pk;
      f32x4 a = acc[m][n];
      pk.h[0] = f2b(fmaxf(a.x + bb0, 0.f));
      pk.h[1] = f2b(fmaxf(a.y + bb1, 0.f));
      pk.h[2] = f2b(fmaxf(a.z + bb2, 0.f));
      pk.h[3] = f2b(fmaxf(a.w + bb3, 0.f));
      *(uint2*)&hs[(n * 16 + lm) * HSTR + f] = pk.v;
    }
  }
  __syncthreads();

  // ---- phase 2: y^T = W2t * h^T ----
  const u16* __restrict__ W2b = W2t + (size_t)bin * 128 * HID;
  f32x4 acc2[2][NT];
  #pragma unroll
  for (int m = 0; m < 2; ++m)
    #pragma unroll
    for (int n = 0; n < NT; ++n)
      acc2[m][n] = f32x4{0.f, 0.f, 0.f, 0.f};

  #pragma unroll 4
  for (int k = 0; k < HID / 32; ++k) {
    const int ko = k * 32 + lq * 8;
    v8s bfr[NT];
    #pragma unroll
    for (int n = 0; n < NT; ++n)
      bfr[n] = *(const v8s*)&hs[(n * 16 + lm) * HSTR + ko];
    #pragma unroll
    for (int m = 0; m < 2; ++m) {
      const v8s af = *(const v8s*)(W2b + (size_t)((w * 2 + m) * 16 + lm) * HID + ko);
      #pragma unroll
      for (int n = 0; n < NT; ++n)
        acc2[m][n] = __builtin_amdgcn_mfma_f32_16x16x32_bf16(af, bfr[n], acc2[m][n], 0, 0, 0);
    }
  }
  const float* b2b = b2 + bin * 128;
  #pragma unroll
  for (int m = 0; m < 2; ++m) {
    const int f = (w * 2 + m) * 16 + lq * 4;
    float bb0 = b2b[f], bb1 = b2b[f + 1], bb2 = b2b[f + 2], bb3 = b2b[f + 3];
    #pragma unroll
    for (int n = 0; n < NT; ++n) {
      if (rowid[n] >= 0) {
        union { u16 h[4]; uint2 v; } pk;
        f32x4 a = acc2[m][n];
        pk.h[0] = f2b(a.x + bb0);
        pk.h[1] = f2b(a.y + bb1);
        pk.h[2] = f2b(a.z + bb2);
        pk.h[3] = f2b(a.w + bb3);
        *(uint2*)(dst + (size_t)rowid[n] * 128 + f) = pk.v;
      }
    }
  }
}

// ==================== attention + concat (fp32) ====================
__global__ __launch_bounds__(128) void attn_k(
    const u16* __restrict__ stmt, const u16* __restrict__ roots,
    const float* __restrict__ themb, const int* __restrict__ thidx,
    const float* __restrict__ wHe, const float* __restrict__ bHe,
    const float* __restrict__ wHg, const float* __restrict__ bHg,
    const float* __restrict__ wHt, const float* __restrict__ bHt,
    float* __restrict__ out)
{
  const int b = blockIdx.x, t = threadIdx.x;   // 128 threads
  __shared__ float obj_s[128], q_s[128], keys_s[16 * 132], a_s[16];

  const float obj = b2f(stmt[((size_t)b * 9 + 8) * 128 + t]);
  obj_s[t] = obj;
  out[(size_t)b * 512 + t] = obj;              // obj passthrough
  __syncthreads();

  for (int a = 0; a < 3; ++a) {               // 0: gt_ctx, 1: ent_ctx, 2: th_ctx
    int cntk;
    const float *Wt, *bv;
    if (a == 0) {
      cntk = 8; Wt = wHg; bv = bHg;
      for (int j = 0; j < 8; ++j)
        keys_s[j * 132 + t] = b2f(stmt[((size_t)b * 9 + j) * 128 + t]);
    } else if (a == 1) {
      cntk = 16; Wt = wHe; bv = bHe;
      for (int j = 0; j < 16; ++j)
        keys_s[j * 132 + t] = b2f(roots[((size_t)b * 34 + j) * 128 + t]);
    } else {
      cntk = 8; Wt = wHt; bv = bHt;           // TH_MAX = 8
      for (int j = 0; j < 8; ++j) {
        int ti = thidx[b * 8 + j] & 31;        // V_TH = 32
        keys_s[j * 132 + t] = themb[(size_t)ti * 128 + t];
      }
    }
    // q[t] = b[t] + sum_k obj[k] * W[k][t]  (raw [in][out] layout, lane-coalesced)
    float qa = bv[t];
    for (int k = 0; k < 128; ++k) qa += obj_s[k] * Wt[k * 128 + t];
    q_s[t] = (qa == qa) ? qa : 0.f;
    __syncthreads();
    if (t < cntk) {
      float sc = 0.f;
      for (int k = 0; k < 128; ++k) sc += keys_s[t * 132 + k] * q_s[k];
      a_s[t] = (sc == sc) ? sc : 0.f;
    }
    __syncthreads();
    if (t == 0) {
      float mx = a_s[0];
      for (int j = 1; j < cntk; ++j) mx = fmaxf(mx, a_s[j]);
      float sm = 0.f;
      for (int j = 0; j < cntk; ++j) { float e = expf(a_s[j] - mx); a_s[j] = e; sm += e; }
      float inv = 1.f / sm;
      for (int j = 0; j < cntk; ++j) a_s[j] *= inv;
    }
    __syncthreads();
    float c = 0.f;
    for (int j = 0; j < cntk; ++j) c += a_s[j] * keys_s[j * 132 + t];
    out[(size_t)b * 512 + 128 * (a + 1) + t] = c;
    __syncthreads();
  }
}

// ==================== launch ====================
extern "C" void kernel_launch(void* const* d_in, const int* in_sizes, int n_in,
                              void* d_out, int out_size, void* d_ws, size_t ws_size,
                              hipStream_t stream)
{
  const int*   leaf_idx = (const int*)d_in[0];
  const int*   nf_ids   = (const int*)d_in[1];
  const int*   lf_ids   = (const int*)d_in[2];
  const int*   th_idx   = (const int*)d_in[3];
  const float* ent_emb  = (const float*)d_in[4];
  const float* th_emb   = (const float*)d_in[5];
  const float* nf_W1 = (const float*)d_in[6];
  const float* nf_b1 = (const float*)d_in[7];
  const float* nf_W2 = (const float*)d_in[8];
  const float* nf_b2 = (const float*)d_in[9];
  const float* lf_W1 = (const float*)d_in[10];
  const float* lf_b1 = (const float*)d_in[11];
  const float* lf_W2 = (const float*)d_in[12];
  const float* lf_b2 = (const float*)d_in[13];
  const float* he_W = (const float*)d_in[14];
  const float* he_b = (const float*)d_in[15];
  const float* hg_W = (const float*)d_in[16];
  const float* hg_b = (const float*)d_in[17];
  const float* ht_W = (const float*)d_in[18];
  const float* ht_b = (const float*)d_in[19];

  // ---- choose chunk size CB (trees per chunk) from ws_size ----
  // footprint ~= 14.5 MB fixed + CB*3312 B (perm 240 + bufA 2048 + bufB 1024)
  int CB = NTREE;                              // 34816 -> full, no chunking
  while (CB > 544 && 14500000ull + (unsigned long long)CB * 3312ull > (unsigned long long)ws_size)
    CB >>= 1;                                  // 34816,17408,8704,4352,2176,1088,544
  const int nch = NTREE / CB;

  char* ws = (char*)d_ws;
  size_t off = 0;
  auto take = [&](size_t bytes) -> char* {
    char* p = ws + off;
    off = (off + bytes + 255) & ~(size_t)255;
    return p;
  };
  int* cnt      = (int*)take(8192);                       // nch*16 node + 8 leaf
  int* leafperm = (int*)take((size_t)3 * RLEAF * 4);      // 110.6 KB
  int* chperm   = (int*)take((size_t)60 * CB * 4);        // 4 bins x 15CB rows
  u16* wN1  = (u16*)take((size_t)4 * 256 * 256 * 2);      // 512 KB
  u16* wN2  = (u16*)take((size_t)4 * 128 * 256 * 2);      // 256 KB
  u16* wL1  = (u16*)take((size_t)3 * 512 * 256 * 2);      // 786 KB
  u16* wL2  = (u16*)take((size_t)3 * 128 * 512 * 2);      // 393 KB
  u16* embB = (u16*)take((size_t)2000 * 128 * 2);         // 512 KB
  u16* bufA  = (u16*)take((size_t)CB * 8 * 128 * 2);      // lvl0 out / lvl2 out
  u16* bufB  = (u16*)take((size_t)CB * 4 * 128 * 2);      // lvl1 out
  u16* roots = (u16*)take((size_t)NTREE * 128 * 2);       // 8.91 MB
  u16* stmt  = (u16*)take((size_t)RLEAF * 128 * 2);       // 2.36 MB

  int* leafcnt = cnt + nch * 16;

  hipMemsetAsync(cnt, 0, (size_t)(nch * 16 + 8) * 4, stream);
  transpose_k<<<4840, 256, 0, stream>>>(nf_W1, nf_W2, lf_W1, lf_W2, ent_emb,
                                        wN1, wN2, wL1, wL2, embB);
  leaf_perm_k<<<36, 256, 0, stream>>>(lf_ids, leafcnt, leafperm);

  for (int c = 0; c < nch; ++c) {
    const int bt0 = c * CB;
    int* ccnt = cnt + c * 16;
    perm_chunk_k<<<(15 * CB + 255) / 256, 256, 0, stream>>>(nf_ids, ccnt, chperm, CB, bt0);
    mlp_k<256, 4, 0, 64><<<CB / 8 + 4, 256, 0, stream>>>(
        nullptr, leaf_idx, embB, chperm, ccnt, 8 * CB, bt0,
        wN1, nf_b1, wN2, nf_b2, bufA);
    mlp_k<256, 4, 1, 64><<<CB / 16 + 4, 256, 0, stream>>>(
        bufA, nullptr, nullptr, chperm + 32 * CB, ccnt + 4, 4 * CB, 0,
        wN1, nf_b1, wN2, nf_b2, bufB);
    mlp_k<256, 4, 1, 64><<<CB / 32 + 4, 256, 0, stream>>>(
        bufB, nullptr, nullptr, chperm + 48 * CB, ccnt + 8, 2 * CB, 0,
        wN1, nf_b1, wN2, nf_b2, bufA);
    mlp_k<256, 4, 1, 64><<<(CB + 63) / 64 + 4, 256, 0, stream>>>(
        bufA, nullptr, nullptr, chperm + 56 * CB, ccnt + 12, CB, 0,
        wN1, nf_b1, wN2, nf_b2, roots + (size_t)bt0 * 128);
  }

  mlp_k<512, 3, 2, 32><<<RLEAF / 32 + 3, 256, 0, stream>>>(
      roots, nullptr, nullptr, leafperm, leafcnt, RLEAF, 0,
      wL1, lf_b1, wL2, lf_b2, stmt);

  attn_k<<<1024, 128, 0, stream>>>(stmt, roots, th_emb, th_idx,
                                   he_W, he_b, hg_W, hg_b, ht_W, ht_b,
                                   (float*)d_out);
}